// Round 1
// baseline (613.319 us; speedup 1.0000x reference)
//
#include <hip/hip_runtime.h>
#include <hip/hip_bf16.h>

typedef short bf16x8 __attribute__((ext_vector_type(8)));
typedef float f32x4 __attribute__((ext_vector_type(4)));

__device__ __forceinline__ float bf2f(unsigned short u){
  union { unsigned int i; float f; } v; v.i = ((unsigned int)u)<<16; return v.f;
}
__device__ __forceinline__ unsigned short f2bf(float f){
  union { float f; unsigned int i; } v; v.f = f;
  unsigned int i = v.i;
  return (unsigned short)((i + 0x7fffu + ((i>>16)&1u)) >> 16);  // RNE
}

// ---------------- CSR build ----------------
__global__ void k_zero(int* p, int n){
  int i = blockIdx.x*256 + threadIdx.x;
  if(i<n) p[i] = 0;
}

__global__ void k_hist(const int* dst, int* deg, int ne){
  int e = blockIdx.x*256 + threadIdx.x;
  if(e<ne) atomicAdd(&deg[dst[e]], 1);
}

__global__ void k_partial(const int* deg, int* part, int n){
  __shared__ int sm[256];
  int i = blockIdx.x*256 + threadIdx.x;
  sm[threadIdx.x] = (i<n) ? deg[i] : 0;
  __syncthreads();
  for(int s=128; s>0; s>>=1){
    if(threadIdx.x < s) sm[threadIdx.x] += sm[threadIdx.x+s];
    __syncthreads();
  }
  if(threadIdx.x==0) part[blockIdx.x] = sm[0];
}

__global__ void k_scanp(const int* part, int* ppre, int nb){
  __shared__ int sm[512];
  int t = threadIdx.x;
  sm[t] = (t<nb) ? part[t] : 0;
  __syncthreads();
  for(int off=1; off<512; off<<=1){
    int v = sm[t];
    int a = (t>=off) ? sm[t-off] : 0;
    __syncthreads();
    sm[t] = v + a;
    __syncthreads();
  }
  if(t<nb) ppre[t] = (t==0) ? 0 : sm[t-1];
}

__global__ void k_offsets(int* deg_cursor, const int* ppre, int* row_off, int n){
  __shared__ int sm[256];
  int i = blockIdx.x*256 + threadIdx.x, t = threadIdx.x;
  int v = (i<n) ? deg_cursor[i] : 0;
  sm[t] = v;
  __syncthreads();
  for(int off=1; off<256; off<<=1){
    int x = sm[t];
    int a = (t>=off) ? sm[t-off] : 0;
    __syncthreads();
    sm[t] = x + a;
    __syncthreads();
  }
  int excl = ppre[blockIdx.x] + sm[t] - v;
  if(i<n){
    row_off[i] = excl;
    deg_cursor[i] = excl;          // becomes the fill cursor
    if(i==n-1) row_off[n] = excl + v;
  }
}

__global__ void k_fill(const int* src, const int* dst, int* cursor, int* csr, int ne){
  int e = blockIdx.x*256 + threadIdx.x;
  if(e<ne){
    int p = atomicAdd(&cursor[dst[e]], 1);
    csr[p] = src[e];
  }
}

// ---------------- feature prep ----------------
// A0 row layout: [mean(128) | x(128)] bf16, stride 256. Writes x part.
__global__ void k_cast_x(const float* emb, const int* n_id, unsigned short* A0, int n){
  int gid = blockIdx.x*256 + threadIdx.x;      // n*32 threads, 4 cols each
  int row = gid >> 5, c4 = (gid & 31) * 4;
  if(row >= n) return;
  float4 v = *(const float4*)&emb[(long)n_id[row]*128 + c4];
  ushort4 o;
  o.x = f2bf(v.x); o.y = f2bf(v.y); o.z = f2bf(v.z); o.w = f2bf(v.w);
  *(ushort4*)&A0[(long)row*256 + 128 + c4] = o;
}

// wcat[n][k] = bf16( k<128 ? Wl[n][k] : Wr[n][k-128] ), [128][256]
__global__ void k_wcat(const float* Wl, const float* Wr, unsigned short* wc){
  int i = blockIdx.x*256 + threadIdx.x;
  if(i >= 128*256) return;
  int nn = i >> 8, k = i & 255;
  float v = (k<128) ? Wl[nn*128 + k] : Wr[nn*128 + k - 128];
  wc[i] = f2bf(v);
}

// ---------------- mean aggregation: one wave per node ----------------
__global__ void k_agg(const unsigned short* X, unsigned short* Mout,
                      const int* row_off, const int* csr, int n){
  int w = (blockIdx.x*blockDim.x + threadIdx.x) >> 6;
  int lane = threadIdx.x & 63;
  if(w >= n) return;
  int beg = row_off[w], end = row_off[w+1];
  float a0 = 0.f, a1 = 0.f;
  for(int e=beg; e<end; ++e){
    int s = csr[e];                                   // wave-uniform -> s_load
    unsigned int v = *(const unsigned int*)&X[(long)s*256 + 128 + lane*2];
    a0 += bf2f((unsigned short)(v & 0xffffu));
    a1 += bf2f((unsigned short)(v >> 16));
  }
  int deg = end - beg;
  float inv = (deg>0) ? 1.0f/(float)deg : 0.f;
  a0 *= inv; a1 *= inv;
  unsigned int o = ((unsigned int)f2bf(a1) << 16) | (unsigned int)f2bf(a0);
  *(unsigned int*)&Mout[(long)w*256 + lane*2] = o;
}

// ---------------- GEMM: C[M,128] = A[M,256] @ Wcat^T + bias ----------------
// block = 256 thr = 4 waves, each wave 16 rows. W (64KB bf16) in LDS, XOR-swizzled.
template<int RELU, int OUTSTRIDE, int OUTOFF>
__global__ __launch_bounds__(256,2) void k_gemm(const unsigned short* A,
                                                const unsigned short* wc,
                                                const float* bias,
                                                unsigned short* out, int nrows){
  __shared__ unsigned short Wl[32768];   // 128 rows x 256 cols bf16 = 64KB
  int tid = threadIdx.x;
  // stage W into LDS with st-swizzle: byte ^= (row&7)<<4
  for(int it=0; it<16; ++it){
    int idx  = it*256 + tid;       // 16B chunk id, 4096 total
    int byte = idx*16;
    int row  = byte >> 9;
    int swz  = byte ^ ((row & 7) << 4);
    *(uint4*)((char*)Wl + swz) = *(const uint4*)((const char*)wc + byte);
  }
  __syncthreads();

  int lane = tid & 63, wv = tid >> 6;
  int rowA = blockIdx.x*64 + wv*16 + (lane & 15);
  int rcl  = rowA < nrows ? rowA : nrows-1;
  const char* Ab = (const char*)(A + (long)rcl*256) + ((lane>>4)*16);
  bf16x8 a[8];
#pragma unroll
  for(int k=0;k<8;++k) a[k] = *(const bf16x8*)(Ab + k*64);

  f32x4 acc[8];
#pragma unroll
  for(int i=0;i<8;++i) acc[i] = (f32x4){0.f,0.f,0.f,0.f};

#pragma unroll
  for(int nf=0; nf<8; ++nf){
    int rw = nf*16 + (lane & 15);
#pragma unroll
    for(int k=0;k<8;++k){
      int byte = (rw*512 + k*64 + (lane>>4)*16) ^ ((rw & 7) << 4);
      bf16x8 b = *(const bf16x8*)((const char*)Wl + byte);
      acc[nf] = __builtin_amdgcn_mfma_f32_16x16x32_bf16(a[k], b, acc[nf], 0, 0, 0);
    }
  }

  int rbase = blockIdx.x*64 + wv*16 + (lane>>4)*4;
#pragma unroll
  for(int nf=0; nf<8; ++nf){
    int col = nf*16 + (lane & 15);
    float bs = bias[col];
#pragma unroll
    for(int r=0;r<4;++r){
      int row = rbase + r;
      if(row < nrows){
        float v = acc[nf][r] + bs;
        if(RELU) v = v > 0.f ? v : 0.f;
        out[(long)row*OUTSTRIDE + OUTOFF + col] = f2bf(v);
      }
    }
  }
}

// ---------------- edge-label dot: one wave per pair ----------------
__global__ void k_dot(const unsigned short* z, const int* s, const int* d,
                      float* out, int nl){
  int w = (blockIdx.x*256 + threadIdx.x) >> 6;
  int lane = threadIdx.x & 63;
  if(w >= nl) return;
  int si = s[w], di = d[w];
  unsigned int a = *(const unsigned int*)&z[(long)si*128 + lane*2];
  unsigned int b = *(const unsigned int*)&z[(long)di*128 + lane*2];
  float acc = bf2f((unsigned short)(a & 0xffffu)) * bf2f((unsigned short)(b & 0xffffu))
            + bf2f((unsigned short)(a >> 16))     * bf2f((unsigned short)(b >> 16));
  for(int off=32; off; off>>=1) acc += __shfl_down(acc, off);
  if(lane==0) out[w] = acc;
}

extern "C" void kernel_launch(void* const* d_in, const int* in_sizes, int n_in,
                              void* d_out, int out_size, void* d_ws, size_t ws_size,
                              hipStream_t stream){
  const int N  = in_sizes[0];
  const int NE = in_sizes[1] / 2;
  const int NL = in_sizes[2] / 2;
  const int*   n_id = (const int*)d_in[0];
  const int*   src  = (const int*)d_in[1];
  const int*   dst  = src + NE;
  const int*   ls   = (const int*)d_in[2];
  const int*   ld   = ls + NL;
  const float* emb  = (const float*)d_in[3];
  const float* Wl0  = (const float*)d_in[4];
  const float* bl0  = (const float*)d_in[5];
  const float* Wr0  = (const float*)d_in[6];
  const float* Wl1  = (const float*)d_in[7];
  const float* bl1  = (const float*)d_in[8];
  const float* Wr1  = (const float*)d_in[9];
  float* out = (float*)d_out;

  char* ws = (char*)d_ws;
  size_t off = 0;
  auto alloc = [&](size_t bytes)->char*{
    char* p = ws + off;
    off = (off + bytes + 255) & ~(size_t)255;
    return p;
  };
  unsigned short* A0   = (unsigned short*)alloc((size_t)N*256*2);   // [mean0|x]
  unsigned short* A1   = (unsigned short*)alloc((size_t)N*256*2);   // [mean1|h]
  int* row_off         = (int*)alloc((size_t)(N+1)*4);
  int* cursor          = (int*)alloc((size_t)N*4);
  int* csr             = (int*)alloc((size_t)NE*4);
  int* part            = (int*)alloc(4096);
  int* ppre            = (int*)alloc(4096);
  unsigned short* wc0  = (unsigned short*)alloc(128*256*2);
  unsigned short* wc1  = (unsigned short*)alloc(128*256*2);
  unsigned short* Z    = A0;   // reuse A0 for z [N][128]

  const int NB = (N + 255) / 256;
  hipLaunchKernelGGL(k_zero,    dim3(NB),            dim3(256), 0, stream, cursor, N);
  hipLaunchKernelGGL(k_hist,    dim3((NE+255)/256),  dim3(256), 0, stream, dst, cursor, NE);
  hipLaunchKernelGGL(k_partial, dim3(NB),            dim3(256), 0, stream, cursor, part, N);
  hipLaunchKernelGGL(k_scanp,   dim3(1),             dim3(512), 0, stream, part, ppre, NB);
  hipLaunchKernelGGL(k_offsets, dim3(NB),            dim3(256), 0, stream, cursor, ppre, row_off, N);
  hipLaunchKernelGGL(k_fill,    dim3((NE+255)/256),  dim3(256), 0, stream, src, dst, cursor, csr, NE);
  hipLaunchKernelGGL(k_cast_x,  dim3((N*32+255)/256),dim3(256), 0, stream, emb, n_id, A0, N);
  hipLaunchKernelGGL(k_wcat,    dim3(128),           dim3(256), 0, stream, Wl0, Wr0, wc0);
  hipLaunchKernelGGL(k_wcat,    dim3(128),           dim3(256), 0, stream, Wl1, Wr1, wc1);
  // layer 0
  hipLaunchKernelGGL(k_agg,     dim3((N*64+255)/256),dim3(256), 0, stream, A0, A0, row_off, csr, N);
  hipLaunchKernelGGL((k_gemm<1,256,128>), dim3((N+63)/64), dim3(256), 0, stream, A0, wc0, bl0, A1, N);
  // layer 1
  hipLaunchKernelGGL(k_agg,     dim3((N*64+255)/256),dim3(256), 0, stream, A1, A1, row_off, csr, N);
  hipLaunchKernelGGL((k_gemm<0,128,0>),   dim3((N+63)/64), dim3(256), 0, stream, A1, wc1, bl1, Z, N);
  // edge-label dots
  hipLaunchKernelGGL(k_dot,     dim3((NL*64+255)/256),dim3(256), 0, stream, Z, ls, ld, out, NL);
}

// Round 2
// 411.940 us; speedup vs baseline: 1.4889x; 1.4889x over previous
//
#include <hip/hip_runtime.h>
#include <hip/hip_bf16.h>

typedef short bf16x8 __attribute__((ext_vector_type(8)));
typedef float f32x4 __attribute__((ext_vector_type(4)));

__device__ __forceinline__ float bf2f(unsigned short u){
  union { unsigned int i; float f; } v; v.i = ((unsigned int)u)<<16; return v.f;
}
__device__ __forceinline__ unsigned short f2bf(float f){
  union { float f; unsigned int i; } v; v.f = f;
  unsigned int i = v.i;
  return (unsigned short)((i + 0x7fffu + ((i>>16)&1u)) >> 16);  // RNE
}
__device__ __forceinline__ void acc2(unsigned int v, float& a0, float& a1){
  a0 += bf2f((unsigned short)(v & 0xffffu));
  a1 += bf2f((unsigned short)(v >> 16));
}

// ---------------- CSR build ----------------
__global__ void k_zero(int* p, int n){
  int i = blockIdx.x*256 + threadIdx.x;
  if(i<n) p[i] = 0;
}

__global__ void k_hist(const int* dst, int* deg, int ne){
  int e = blockIdx.x*256 + threadIdx.x;
  if(e<ne) atomicAdd(&deg[dst[e]], 1);
}

__global__ void k_partial(const int* deg, int* part, int n){
  __shared__ int sm[256];
  int i = blockIdx.x*256 + threadIdx.x;
  sm[threadIdx.x] = (i<n) ? deg[i] : 0;
  __syncthreads();
  for(int s=128; s>0; s>>=1){
    if(threadIdx.x < s) sm[threadIdx.x] += sm[threadIdx.x+s];
    __syncthreads();
  }
  if(threadIdx.x==0) part[blockIdx.x] = sm[0];
}

__global__ void k_scanp(const int* part, int* ppre, int nb){
  __shared__ int sm[512];
  int t = threadIdx.x;
  sm[t] = (t<nb) ? part[t] : 0;
  __syncthreads();
  for(int off=1; off<512; off<<=1){
    int v = sm[t];
    int a = (t>=off) ? sm[t-off] : 0;
    __syncthreads();
    sm[t] = v + a;
    __syncthreads();
  }
  if(t<nb) ppre[t] = (t==0) ? 0 : sm[t-1];
}

__global__ void k_offsets(int* deg_cursor, const int* ppre, int* row_off, int n){
  __shared__ int sm[256];
  int i = blockIdx.x*256 + threadIdx.x, t = threadIdx.x;
  int v = (i<n) ? deg_cursor[i] : 0;
  sm[t] = v;
  __syncthreads();
  for(int off=1; off<256; off<<=1){
    int x = sm[t];
    int a = (t>=off) ? sm[t-off] : 0;
    __syncthreads();
    sm[t] = x + a;
    __syncthreads();
  }
  int excl = ppre[blockIdx.x] + sm[t] - v;
  if(i<n){
    row_off[i] = excl;
    deg_cursor[i] = excl;          // becomes the fill cursor
    if(i==n-1) row_off[n] = excl + v;
  }
}

__global__ void k_fill(const int* src, const int* dst, int* cursor, int* csr, int ne){
  int e = blockIdx.x*256 + threadIdx.x;
  if(e<ne){
    int p = atomicAdd(&cursor[dst[e]], 1);
    csr[p] = src[e];
  }
}

// ---------------- feature prep ----------------
// A0 row layout: [mean(128) | x(128)] bf16, stride 256. Writes x part.
__global__ void k_cast_x(const float* emb, const int* n_id, unsigned short* A0, int n){
  int gid = blockIdx.x*256 + threadIdx.x;      // n*32 threads, 4 cols each
  int row = gid >> 5, c4 = (gid & 31) * 4;
  if(row >= n) return;
  float4 v = *(const float4*)&emb[(long)n_id[row]*128 + c4];
  ushort4 o;
  o.x = f2bf(v.x); o.y = f2bf(v.y); o.z = f2bf(v.z); o.w = f2bf(v.w);
  *(ushort4*)&A0[(long)row*256 + 128 + c4] = o;
}

// wcat[n][k] = bf16( k<128 ? Wl[n][k] : Wr[n][k-128] ), [128][256]
__global__ void k_wcat(const float* Wl, const float* Wr, unsigned short* wc){
  int i = blockIdx.x*256 + threadIdx.x;
  if(i >= 128*256) return;
  int nn = i >> 8, k = i & 255;
  float v = (k<128) ? Wl[nn*128 + k] : Wr[nn*128 + k - 128];
  wc[i] = f2bf(v);
}

// ---------------- mean aggregation: one wave per node, 8-deep gather pipeline ----------------
__global__ void k_agg(const unsigned short* X, unsigned short* Mout,
                      const int* row_off, const int* csr, int n){
  int w = (blockIdx.x*blockDim.x + threadIdx.x) >> 6;
  int lane = threadIdx.x & 63;
  if(w >= n) return;
  int beg = row_off[w], end = row_off[w+1];
  int deg = end - beg;
  float a0 = 0.f, a1 = 0.f;
  const char* Xb = (const char*)X + 256;     // x-half of the 512B row
  for(int base=0; base<deg; base+=64){
    int cnt = deg - base; if(cnt>64) cnt=64;
    int c1 = cnt - 1;
    // one coalesced load stages up to 64 indices into a register
    int idx = csr[beg + base + (lane < cnt ? lane : c1)];
    for(int j=0; j<cnt; j+=8){
      int j1=j+1>c1?c1:j+1, j2=j+2>c1?c1:j+2, j3=j+3>c1?c1:j+3;
      int j4=j+4>c1?c1:j+4, j5=j+5>c1?c1:j+5, j6=j+6>c1?c1:j+6, j7=j+7>c1?c1:j+7;
      int s0 = __builtin_amdgcn_readlane(idx, j);
      int s1 = __builtin_amdgcn_readlane(idx, j1);
      int s2 = __builtin_amdgcn_readlane(idx, j2);
      int s3 = __builtin_amdgcn_readlane(idx, j3);
      int s4 = __builtin_amdgcn_readlane(idx, j4);
      int s5 = __builtin_amdgcn_readlane(idx, j5);
      int s6 = __builtin_amdgcn_readlane(idx, j6);
      int s7 = __builtin_amdgcn_readlane(idx, j7);
      unsigned int v0 = ((const unsigned int*)(Xb + (long)s0*512))[lane];
      unsigned int v1 = ((const unsigned int*)(Xb + (long)s1*512))[lane];
      unsigned int v2 = ((const unsigned int*)(Xb + (long)s2*512))[lane];
      unsigned int v3 = ((const unsigned int*)(Xb + (long)s3*512))[lane];
      unsigned int v4 = ((const unsigned int*)(Xb + (long)s4*512))[lane];
      unsigned int v5 = ((const unsigned int*)(Xb + (long)s5*512))[lane];
      unsigned int v6 = ((const unsigned int*)(Xb + (long)s6*512))[lane];
      unsigned int v7 = ((const unsigned int*)(Xb + (long)s7*512))[lane];
      acc2(v0, a0, a1);
      if(j+1<cnt) acc2(v1, a0, a1);
      if(j+2<cnt) acc2(v2, a0, a1);
      if(j+3<cnt) acc2(v3, a0, a1);
      if(j+4<cnt) acc2(v4, a0, a1);
      if(j+5<cnt) acc2(v5, a0, a1);
      if(j+6<cnt) acc2(v6, a0, a1);
      if(j+7<cnt) acc2(v7, a0, a1);
    }
  }
  float inv = (deg>0) ? 1.0f/(float)deg : 0.f;
  a0 *= inv; a1 *= inv;
  unsigned int o = ((unsigned int)f2bf(a1) << 16) | (unsigned int)f2bf(a0);
  *(unsigned int*)((char*)Mout + (long)w*512 + lane*4) = o;
}

// ---------------- GEMM: C[M,128] = A[M,256] @ Wcat^T + bias ----------------
// block = 256 thr = 4 waves, each wave 16 rows. W (64KB bf16) in LDS, XOR-swizzled.
template<int RELU, int OUTSTRIDE, int OUTOFF>
__global__ __launch_bounds__(256,2) void k_gemm(const unsigned short* A,
                                                const unsigned short* wc,
                                                const float* bias,
                                                unsigned short* out, int nrows){
  __shared__ unsigned short Wl[32768];   // 128 rows x 256 cols bf16 = 64KB
  int tid = threadIdx.x;
  // stage W into LDS with st-swizzle: byte ^= (row&7)<<4
  for(int it=0; it<16; ++it){
    int idx  = it*256 + tid;       // 16B chunk id, 4096 total
    int byte = idx*16;
    int row  = byte >> 9;
    int swz  = byte ^ ((row & 7) << 4);
    *(uint4*)((char*)Wl + swz) = *(const uint4*)((const char*)wc + byte);
  }
  __syncthreads();

  int lane = tid & 63, wv = tid >> 6;
  int rowA = blockIdx.x*64 + wv*16 + (lane & 15);
  int rcl  = rowA < nrows ? rowA : nrows-1;
  const char* Ab = (const char*)(A + (long)rcl*256) + ((lane>>4)*16);
  bf16x8 a[8];
#pragma unroll
  for(int k=0;k<8;++k) a[k] = *(const bf16x8*)(Ab + k*64);

  f32x4 acc[8];
#pragma unroll
  for(int i=0;i<8;++i) acc[i] = (f32x4){0.f,0.f,0.f,0.f};

#pragma unroll
  for(int nf=0; nf<8; ++nf){
    int rw = nf*16 + (lane & 15);
#pragma unroll
    for(int k=0;k<8;++k){
      int byte = (rw*512 + k*64 + (lane>>4)*16) ^ ((rw & 7) << 4);
      bf16x8 b = *(const bf16x8*)((const char*)Wl + byte);
      acc[nf] = __builtin_amdgcn_mfma_f32_16x16x32_bf16(a[k], b, acc[nf], 0, 0, 0);
    }
  }

  int rbase = blockIdx.x*64 + wv*16 + (lane>>4)*4;
#pragma unroll
  for(int nf=0; nf<8; ++nf){
    int col = nf*16 + (lane & 15);
    float bs = bias[col];
#pragma unroll
    for(int r=0;r<4;++r){
      int row = rbase + r;
      if(row < nrows){
        float v = acc[nf][r] + bs;
        if(RELU) v = v > 0.f ? v : 0.f;
        out[(long)row*OUTSTRIDE + OUTOFF + col] = f2bf(v);
      }
    }
  }
}

// ---------------- edge-label dot: 4 pairs per wave, 16 lanes x 16B per row ----------------
__global__ void k_dot(const unsigned short* z, const int* s, const int* d,
                      float* out, int nl){
  int wv = (blockIdx.x*256 + threadIdx.x) >> 6;   // wave id
  int lane = threadIdx.x & 63;
  int g = lane >> 4;                               // group 0..3 (one pair each)
  int gl = lane & 15;                              // lane within group
  int pi = wv*4 + g;
  float acc = 0.f;
  if(pi < nl){
    int si = s[pi], di = d[pi];
    bf16x8 va = *(const bf16x8*)&z[(long)si*128 + gl*8];
    bf16x8 vb = *(const bf16x8*)&z[(long)di*128 + gl*8];
#pragma unroll
    for(int i=0;i<8;++i)
      acc += bf2f((unsigned short)va[i]) * bf2f((unsigned short)vb[i]);
#pragma unroll
    for(int off=1; off<16; off<<=1)
      acc += __shfl_xor(acc, off, 16);
    if(gl==0) out[pi] = acc;
  }
}

extern "C" void kernel_launch(void* const* d_in, const int* in_sizes, int n_in,
                              void* d_out, int out_size, void* d_ws, size_t ws_size,
                              hipStream_t stream){
  const int N  = in_sizes[0];
  const int NE = in_sizes[1] / 2;
  const int NL = in_sizes[2] / 2;
  const int*   n_id = (const int*)d_in[0];
  const int*   src  = (const int*)d_in[1];
  const int*   dst  = src + NE;
  const int*   ls   = (const int*)d_in[2];
  const int*   ld   = ls + NL;
  const float* emb  = (const float*)d_in[3];
  const float* Wl0  = (const float*)d_in[4];
  const float* bl0  = (const float*)d_in[5];
  const float* Wr0  = (const float*)d_in[6];
  const float* Wl1  = (const float*)d_in[7];
  const float* bl1  = (const float*)d_in[8];
  const float* Wr1  = (const float*)d_in[9];
  float* out = (float*)d_out;

  char* ws = (char*)d_ws;
  size_t off = 0;
  auto alloc = [&](size_t bytes)->char*{
    char* p = ws + off;
    off = (off + bytes + 255) & ~(size_t)255;
    return p;
  };
  unsigned short* A0   = (unsigned short*)alloc((size_t)N*256*2);   // [mean0|x]
  unsigned short* A1   = (unsigned short*)alloc((size_t)N*256*2);   // [mean1|h]
  int* row_off         = (int*)alloc((size_t)(N+1)*4);
  int* cursor          = (int*)alloc((size_t)N*4);
  int* csr             = (int*)alloc((size_t)NE*4);
  int* part            = (int*)alloc(4096);
  int* ppre            = (int*)alloc(4096);
  unsigned short* wc0  = (unsigned short*)alloc(128*256*2);
  unsigned short* wc1  = (unsigned short*)alloc(128*256*2);
  unsigned short* Z    = A0;   // reuse A0 for z [N][128]

  const int NB = (N + 255) / 256;
  hipLaunchKernelGGL(k_zero,    dim3(NB),            dim3(256), 0, stream, cursor, N);
  hipLaunchKernelGGL(k_hist,    dim3((NE+255)/256),  dim3(256), 0, stream, dst, cursor, NE);
  hipLaunchKernelGGL(k_partial, dim3(NB),            dim3(256), 0, stream, cursor, part, N);
  hipLaunchKernelGGL(k_scanp,   dim3(1),             dim3(512), 0, stream, part, ppre, NB);
  hipLaunchKernelGGL(k_offsets, dim3(NB),            dim3(256), 0, stream, cursor, ppre, row_off, N);
  hipLaunchKernelGGL(k_fill,    dim3((NE+255)/256),  dim3(256), 0, stream, src, dst, cursor, csr, NE);
  hipLaunchKernelGGL(k_cast_x,  dim3((N*32+255)/256),dim3(256), 0, stream, emb, n_id, A0, N);
  hipLaunchKernelGGL(k_wcat,    dim3(128),           dim3(256), 0, stream, Wl0, Wr0, wc0);
  hipLaunchKernelGGL(k_wcat,    dim3(128),           dim3(256), 0, stream, Wl1, Wr1, wc1);
  // layer 0
  hipLaunchKernelGGL(k_agg,     dim3((N*64+255)/256),dim3(256), 0, stream, A0, A0, row_off, csr, N);
  hipLaunchKernelGGL((k_gemm<1,256,128>), dim3((N+63)/64), dim3(256), 0, stream, A0, wc0, bl0, A1, N);
  // layer 1
  hipLaunchKernelGGL(k_agg,     dim3((N*64+255)/256),dim3(256), 0, stream, A1, A1, row_off, csr, N);
  hipLaunchKernelGGL((k_gemm<0,128,0>),   dim3((N+63)/64), dim3(256), 0, stream, A1, wc1, bl1, Z, N);
  // edge-label dots
  hipLaunchKernelGGL(k_dot,     dim3((NL+15)/16),    dim3(256), 0, stream, Z, ls, ld, out, NL);
}

// Round 3
// 369.704 us; speedup vs baseline: 1.6589x; 1.1142x over previous
//
#include <hip/hip_runtime.h>
#include <hip/hip_bf16.h>

typedef short bf16x8 __attribute__((ext_vector_type(8)));
typedef float f32x4 __attribute__((ext_vector_type(4)));

__device__ __forceinline__ float bf2f(unsigned short u){
  union { unsigned int i; float f; } v; v.i = ((unsigned int)u)<<16; return v.f;
}
__device__ __forceinline__ unsigned short f2bf(float f){
  union { float f; unsigned int i; } v; v.f = f;
  unsigned int i = v.i;
  return (unsigned short)((i + 0x7fffu + ((i>>16)&1u)) >> 16);  // RNE
}
__device__ __forceinline__ void acc2(unsigned int v, float& a0, float& a1){
  a0 += bf2f((unsigned short)(v & 0xffffu));
  a1 += bf2f((unsigned short)(v >> 16));
}

// ---------------- CSR build (XCD-sliced: slot = blockIdx & 7 -> node range) ----------------
__global__ void k_zero(int* p, int n){
  int i = blockIdx.x*256 + threadIdx.x;
  if(i<n) p[i] = 0;
}

// grid = nchunk*8; block handles 4096 edges of chunk (blockIdx>>3), keeps dst in its slot range
__global__ void k_hist8(const int* dst, int* deg, int ne, int n){
  int slot = blockIdx.x & 7, chunk = blockIdx.x >> 3;
  int nr = (n + 7) >> 3;
  int lo = slot * nr, hi = lo + nr; if(hi > n) hi = n;
  int base = chunk * 4096;
#pragma unroll
  for(int i=0;i<16;++i){
    int e = base + i*256 + threadIdx.x;
    if(e < ne){
      int d = dst[e];
      if(d >= lo && d < hi) atomicAdd(&deg[d], 1);
    }
  }
}

__global__ void k_partial(const int* deg, int* part, int n){
  __shared__ int sm[256];
  int i = blockIdx.x*256 + threadIdx.x;
  sm[threadIdx.x] = (i<n) ? deg[i] : 0;
  __syncthreads();
  for(int s=128; s>0; s>>=1){
    if(threadIdx.x < s) sm[threadIdx.x] += sm[threadIdx.x+s];
    __syncthreads();
  }
  if(threadIdx.x==0) part[blockIdx.x] = sm[0];
}

__global__ void k_scanp(const int* part, int* ppre, int nb){
  __shared__ int sm[512];
  int t = threadIdx.x;
  sm[t] = (t<nb) ? part[t] : 0;
  __syncthreads();
  for(int off=1; off<512; off<<=1){
    int v = sm[t];
    int a = (t>=off) ? sm[t-off] : 0;
    __syncthreads();
    sm[t] = v + a;
    __syncthreads();
  }
  if(t<nb) ppre[t] = (t==0) ? 0 : sm[t-1];
}

__global__ void k_offsets(int* deg_cursor, const int* ppre, int* row_off, int n){
  __shared__ int sm[256];
  int i = blockIdx.x*256 + threadIdx.x, t = threadIdx.x;
  int v = (i<n) ? deg_cursor[i] : 0;
  sm[t] = v;
  __syncthreads();
  for(int off=1; off<256; off<<=1){
    int x = sm[t];
    int a = (t>=off) ? sm[t-off] : 0;
    __syncthreads();
    sm[t] = x + a;
    __syncthreads();
  }
  int excl = ppre[blockIdx.x] + sm[t] - v;
  if(i<n){
    row_off[i] = excl;
    deg_cursor[i] = excl;          // becomes the fill cursor
    if(i==n-1) row_off[n] = excl + v;
  }
}

__global__ void k_fill8(const int* src, const int* dst, int* cursor, int* csr,
                        int ne, int n){
  int slot = blockIdx.x & 7, chunk = blockIdx.x >> 3;
  int nr = (n + 7) >> 3;
  int lo = slot * nr, hi = lo + nr; if(hi > n) hi = n;
  int base = chunk * 4096;
#pragma unroll
  for(int i=0;i<16;++i){
    int e = base + i*256 + threadIdx.x;
    if(e < ne){
      int d = dst[e];
      int s = src[e];
      if(d >= lo && d < hi){
        int p = atomicAdd(&cursor[d], 1);
        csr[p] = s;
      }
    }
  }
}

// ---------------- feature prep ----------------
// A0 row layout: [mean(128) | x(128)] bf16, stride 256. Writes x part.
__global__ void k_cast_x(const float* emb, const int* n_id, unsigned short* A0, int n){
  int gid = blockIdx.x*256 + threadIdx.x;      // n*32 threads, 4 cols each
  int row = gid >> 5, c4 = (gid & 31) * 4;
  if(row >= n) return;
  float4 v = *(const float4*)&emb[(long)n_id[row]*128 + c4];
  ushort4 o;
  o.x = f2bf(v.x); o.y = f2bf(v.y); o.z = f2bf(v.z); o.w = f2bf(v.w);
  *(ushort4*)&A0[(long)row*256 + 128 + c4] = o;
}

// wcat[n][k] = bf16( k<128 ? Wl[n][k] : Wr[n][k-128] ), [128][256]
__global__ void k_wcat(const float* Wl, const float* Wr, unsigned short* wc){
  int i = blockIdx.x*256 + threadIdx.x;
  if(i >= 128*256) return;
  int nn = i >> 8, k = i & 255;
  float v = (k<128) ? Wl[nn*128 + k] : Wr[nn*128 + k - 128];
  wc[i] = f2bf(v);
}

// ---------------- mean aggregation: one wave per node, 8-deep gather pipeline ----------------
__global__ void k_agg(const unsigned short* X, unsigned short* Mout,
                      const int* row_off, const int* csr, int n){
  int w = (blockIdx.x*blockDim.x + threadIdx.x) >> 6;
  int lane = threadIdx.x & 63;
  if(w >= n) return;
  int beg = row_off[w], end = row_off[w+1];
  int deg = end - beg;
  float a0 = 0.f, a1 = 0.f;
  const char* Xb = (const char*)X + 256;     // x-half of the 512B row
  for(int base=0; base<deg; base+=64){
    int cnt = deg - base; if(cnt>64) cnt=64;
    int c1 = cnt - 1;
    // one coalesced load stages up to 64 indices into a register
    int idx = csr[beg + base + (lane < cnt ? lane : c1)];
    for(int j=0; j<cnt; j+=8){
      int j1=j+1>c1?c1:j+1, j2=j+2>c1?c1:j+2, j3=j+3>c1?c1:j+3;
      int j4=j+4>c1?c1:j+4, j5=j+5>c1?c1:j+5, j6=j+6>c1?c1:j+6, j7=j+7>c1?c1:j+7;
      int s0 = __builtin_amdgcn_readlane(idx, j);
      int s1 = __builtin_amdgcn_readlane(idx, j1);
      int s2 = __builtin_amdgcn_readlane(idx, j2);
      int s3 = __builtin_amdgcn_readlane(idx, j3);
      int s4 = __builtin_amdgcn_readlane(idx, j4);
      int s5 = __builtin_amdgcn_readlane(idx, j5);
      int s6 = __builtin_amdgcn_readlane(idx, j6);
      int s7 = __builtin_amdgcn_readlane(idx, j7);
      unsigned int v0 = ((const unsigned int*)(Xb + (long)s0*512))[lane];
      unsigned int v1 = ((const unsigned int*)(Xb + (long)s1*512))[lane];
      unsigned int v2 = ((const unsigned int*)(Xb + (long)s2*512))[lane];
      unsigned int v3 = ((const unsigned int*)(Xb + (long)s3*512))[lane];
      unsigned int v4 = ((const unsigned int*)(Xb + (long)s4*512))[lane];
      unsigned int v5 = ((const unsigned int*)(Xb + (long)s5*512))[lane];
      unsigned int v6 = ((const unsigned int*)(Xb + (long)s6*512))[lane];
      unsigned int v7 = ((const unsigned int*)(Xb + (long)s7*512))[lane];
      acc2(v0, a0, a1);
      if(j+1<cnt) acc2(v1, a0, a1);
      if(j+2<cnt) acc2(v2, a0, a1);
      if(j+3<cnt) acc2(v3, a0, a1);
      if(j+4<cnt) acc2(v4, a0, a1);
      if(j+5<cnt) acc2(v5, a0, a1);
      if(j+6<cnt) acc2(v6, a0, a1);
      if(j+7<cnt) acc2(v7, a0, a1);
    }
  }
  float inv = (deg>0) ? 1.0f/(float)deg : 0.f;
  a0 *= inv; a1 *= inv;
  unsigned int o = ((unsigned int)f2bf(a1) << 16) | (unsigned int)f2bf(a0);
  *(unsigned int*)((char*)Mout + (long)w*512 + lane*4) = o;
}

// ---------------- GEMM: C[M,128] = A[M,256] @ Wcat^T + bias ----------------
// block = 256 thr = 4 waves; 256 rows per block (4 row-tiles of 64), W staged once.
template<int RELU, int OUTSTRIDE, int OUTOFF>
__global__ __launch_bounds__(256,2) void k_gemm(const unsigned short* A,
                                                const unsigned short* wc,
                                                const float* bias,
                                                unsigned short* out, int nrows){
  __shared__ unsigned short Wl[32768];   // 128 rows x 256 cols bf16 = 64KB
  int tid = threadIdx.x;
  // stage W into LDS with st-swizzle: byte ^= (row&7)<<4
  for(int it=0; it<16; ++it){
    int idx  = it*256 + tid;       // 16B chunk id, 4096 total
    int byte = idx*16;
    int row  = byte >> 9;
    int swz  = byte ^ ((row & 7) << 4);
    *(uint4*)((char*)Wl + swz) = *(const uint4*)((const char*)wc + byte);
  }
  __syncthreads();

  int lane = tid & 63, wv = tid >> 6;
  // hoist bias (per nf fragment, col = nf*16 + (lane&15))
  float bs[8];
#pragma unroll
  for(int nf=0; nf<8; ++nf) bs[nf] = bias[nf*16 + (lane & 15)];

  for(int t=0; t<4; ++t){
    int rowA = blockIdx.x*256 + t*64 + wv*16 + (lane & 15);
    int rcl  = rowA < nrows ? rowA : nrows-1;
    const char* Ab = (const char*)(A + (long)rcl*256) + ((lane>>4)*16);
    bf16x8 a[8];
#pragma unroll
    for(int k=0;k<8;++k) a[k] = *(const bf16x8*)(Ab + k*64);

    f32x4 acc[8];
#pragma unroll
    for(int i=0;i<8;++i) acc[i] = (f32x4){0.f,0.f,0.f,0.f};

#pragma unroll
    for(int nf=0; nf<8; ++nf){
      int rw = nf*16 + (lane & 15);
#pragma unroll
      for(int k=0;k<8;++k){
        int byte = (rw*512 + k*64 + (lane>>4)*16) ^ ((rw & 7) << 4);
        bf16x8 b = *(const bf16x8*)((const char*)Wl + byte);
        acc[nf] = __builtin_amdgcn_mfma_f32_16x16x32_bf16(a[k], b, acc[nf], 0, 0, 0);
      }
    }

    int rbase = blockIdx.x*256 + t*64 + wv*16 + (lane>>4)*4;
#pragma unroll
    for(int nf=0; nf<8; ++nf){
      int col = nf*16 + (lane & 15);
#pragma unroll
      for(int r=0;r<4;++r){
        int row = rbase + r;
        if(row < nrows){
          float v = acc[nf][r] + bs[nf];
          if(RELU) v = v > 0.f ? v : 0.f;
          out[(long)row*OUTSTRIDE + OUTOFF + col] = f2bf(v);
        }
      }
    }
  }
}

// ---------------- edge-label dot: 4 pairs per wave, 16 lanes x 16B per row ----------------
__global__ void k_dot(const unsigned short* z, const int* s, const int* d,
                      float* out, int nl){
  int wv = (blockIdx.x*256 + threadIdx.x) >> 6;   // wave id
  int lane = threadIdx.x & 63;
  int g = lane >> 4;                               // group 0..3 (one pair each)
  int gl = lane & 15;                              // lane within group
  int pi = wv*4 + g;
  float acc = 0.f;
  if(pi < nl){
    int si = s[pi], di = d[pi];
    bf16x8 va = *(const bf16x8*)&z[(long)si*128 + gl*8];
    bf16x8 vb = *(const bf16x8*)&z[(long)di*128 + gl*8];
#pragma unroll
    for(int i=0;i<8;++i)
      acc += bf2f((unsigned short)va[i]) * bf2f((unsigned short)vb[i]);
#pragma unroll
    for(int off=1; off<16; off<<=1)
      acc += __shfl_xor(acc, off, 16);
    if(gl==0) out[pi] = acc;
  }
}

extern "C" void kernel_launch(void* const* d_in, const int* in_sizes, int n_in,
                              void* d_out, int out_size, void* d_ws, size_t ws_size,
                              hipStream_t stream){
  const int N  = in_sizes[0];
  const int NE = in_sizes[1] / 2;
  const int NL = in_sizes[2] / 2;
  const int*   n_id = (const int*)d_in[0];
  const int*   src  = (const int*)d_in[1];
  const int*   dst  = src + NE;
  const int*   ls   = (const int*)d_in[2];
  const int*   ld   = ls + NL;
  const float* emb  = (const float*)d_in[3];
  const float* Wl0  = (const float*)d_in[4];
  const float* bl0  = (const float*)d_in[5];
  const float* Wr0  = (const float*)d_in[6];
  const float* Wl1  = (const float*)d_in[7];
  const float* bl1  = (const float*)d_in[8];
  const float* Wr1  = (const float*)d_in[9];
  float* out = (float*)d_out;

  char* ws = (char*)d_ws;
  size_t off = 0;
  auto alloc = [&](size_t bytes)->char*{
    char* p = ws + off;
    off = (off + bytes + 255) & ~(size_t)255;
    return p;
  };
  unsigned short* A0   = (unsigned short*)alloc((size_t)N*256*2);   // [mean0|x]
  unsigned short* A1   = (unsigned short*)alloc((size_t)N*256*2);   // [mean1|h]
  int* row_off         = (int*)alloc((size_t)(N+1)*4);
  int* cursor          = (int*)alloc((size_t)N*4);
  int* csr             = (int*)alloc((size_t)NE*4);
  int* part            = (int*)alloc(4096);
  int* ppre            = (int*)alloc(4096);
  unsigned short* wc0  = (unsigned short*)alloc(128*256*2);
  unsigned short* wc1  = (unsigned short*)alloc(128*256*2);
  unsigned short* Z    = A0;   // reuse A0 for z [N][128]

  const int NB  = (N + 255) / 256;
  const int NCH = (NE + 4095) / 4096;
  hipLaunchKernelGGL(k_zero,    dim3(NB),            dim3(256), 0, stream, cursor, N);
  hipLaunchKernelGGL(k_hist8,   dim3(NCH*8),         dim3(256), 0, stream, dst, cursor, NE, N);
  hipLaunchKernelGGL(k_partial, dim3(NB),            dim3(256), 0, stream, cursor, part, N);
  hipLaunchKernelGGL(k_scanp,   dim3(1),             dim3(512), 0, stream, part, ppre, NB);
  hipLaunchKernelGGL(k_offsets, dim3(NB),            dim3(256), 0, stream, cursor, ppre, row_off, N);
  hipLaunchKernelGGL(k_fill8,   dim3(NCH*8),         dim3(256), 0, stream, src, dst, cursor, csr, NE, N);
  hipLaunchKernelGGL(k_cast_x,  dim3((N*32+255)/256),dim3(256), 0, stream, emb, n_id, A0, N);
  hipLaunchKernelGGL(k_wcat,    dim3(128),           dim3(256), 0, stream, Wl0, Wr0, wc0);
  hipLaunchKernelGGL(k_wcat,    dim3(128),           dim3(256), 0, stream, Wl1, Wr1, wc1);
  // layer 0
  hipLaunchKernelGGL(k_agg,     dim3((N*64+255)/256),dim3(256), 0, stream, A0, A0, row_off, csr, N);
  hipLaunchKernelGGL((k_gemm<1,256,128>), dim3((N+255)/256), dim3(256), 0, stream, A0, wc0, bl0, A1, N);
  // layer 1
  hipLaunchKernelGGL(k_agg,     dim3((N*64+255)/256),dim3(256), 0, stream, A1, A1, row_off, csr, N);
  hipLaunchKernelGGL((k_gemm<0,128,0>),   dim3((N+255)/256), dim3(256), 0, stream, A1, wc1, bl1, Z, N);
  // edge-label dots
  hipLaunchKernelGGL(k_dot,     dim3((NL+15)/16),    dim3(256), 0, stream, Z, ls, ld, out, NL);
}

// Round 4
// 275.608 us; speedup vs baseline: 2.2253x; 1.3414x over previous
//
#include <hip/hip_runtime.h>
#include <hip/hip_bf16.h>

typedef short bf16x8 __attribute__((ext_vector_type(8)));
typedef float f32x4 __attribute__((ext_vector_type(4)));

#define BKT_SHIFT 9
#define BKT_RANGE 512          // nodes per bucket
#define MAXBKT 256             // N <= 131072

__device__ __forceinline__ float bf2f(unsigned short u){
  union { unsigned int i; float f; } v; v.i = ((unsigned int)u)<<16; return v.f;
}
__device__ __forceinline__ unsigned short f2bf(float f){
  union { float f; unsigned int i; } v; v.f = f;
  unsigned int i = v.i;
  return (unsigned short)((i + 0x7fffu + ((i>>16)&1u)) >> 16);  // RNE
}
__device__ __forceinline__ void acc2(unsigned int v, float& a0, float& a1){
  a0 += bf2f((unsigned short)(v & 0xffffu));
  a1 += bf2f((unsigned short)(v >> 16));
}

// ---------------- bucket-sort CSR build ----------------
__global__ void k_zero(int* p, int n){
  int i = blockIdx.x*256 + threadIdx.x;
  if(i<n) p[i] = 0;
}

// B1: per-block LDS histogram of dst-buckets -> global bucket counts
__global__ void k_bcount(const int* dst, int* gcount, int ne, int nbk){
  __shared__ int cnt[MAXBKT];
  int tid = threadIdx.x;
  if(tid < nbk) cnt[tid] = 0;
  __syncthreads();
  int base = blockIdx.x * 4096;
#pragma unroll
  for(int i=0;i<16;++i){
    int e = base + i*256 + tid;
    if(e < ne) atomicAdd(&cnt[dst[e] >> BKT_SHIFT], 1);
  }
  __syncthreads();
  if(tid < nbk && cnt[tid] > 0) atomicAdd(&gcount[tid], cnt[tid]);
}

// B2: exclusive scan of bucket counts -> base & cursor
__global__ void k_bscan(const int* gcount, int* gbase, int* gcursor, int nbk){
  __shared__ int sm[256];
  int t = threadIdx.x;
  int v = (t<nbk) ? gcount[t] : 0;
  sm[t] = v;
  __syncthreads();
  for(int off=1; off<256; off<<=1){
    int a = (t>=off) ? sm[t-off] : 0;
    __syncthreads();
    sm[t] += a;
    __syncthreads();
  }
  if(t<nbk){
    int excl = sm[t] - v;
    gbase[t] = excl;
    gcursor[t] = excl;
  }
}

// B3: scatter (s,d) into bucket-partitioned ebuf via LDS ranking
__global__ void k_bscatter(const int* src, const int* dst, int* gcursor,
                           int2* ebuf, int ne, int nbk){
  __shared__ int cnt[MAXBKT];
  __shared__ int runbase[MAXBKT];
  int tid = threadIdx.x;
  if(tid < nbk) cnt[tid] = 0;
  __syncthreads();
  int base = blockIdx.x * 4096;
  int se[16], de[16], re[16];
#pragma unroll
  for(int i=0;i<16;++i){
    int e = base + i*256 + tid;
    if(e < ne){
      de[i] = dst[e];
      se[i] = src[e];
      re[i] = atomicAdd(&cnt[de[i] >> BKT_SHIFT], 1);
    } else de[i] = -1;
  }
  __syncthreads();
  if(tid < nbk) runbase[tid] = cnt[tid] ? atomicAdd(&gcursor[tid], cnt[tid]) : 0;
  __syncthreads();
#pragma unroll
  for(int i=0;i<16;++i){
    if(de[i] >= 0){
      int pos = runbase[de[i] >> BKT_SHIFT] + re[i];
      ebuf[pos] = make_int2(se[i], de[i]);
    }
  }
}

// B4: per-bucket counting sort -> csr + row_off. grid = nbk, block = 512.
__global__ void k_bsort(const int2* ebuf, const int* gbase, const int* gcursor,
                        int* csr, int* row_off, int n, int ne, int nbk){
  __shared__ int h[BKT_RANGE];
  __shared__ int cur[BKT_RANGE];
  int t = threadIdx.x;
  int k = blockIdx.x;
  int lo = k << BKT_SHIFT;
  int beg = gbase[k], end = gcursor[k];
  h[t] = 0;
  __syncthreads();
  for(int e = beg + t; e < end; e += 512)
    atomicAdd(&h[ebuf[e].y - lo], 1);
  __syncthreads();
  int v = h[t];
  // inclusive scan over 512
  __shared__ int sm[512];
  sm[t] = v;
  __syncthreads();
  for(int off=1; off<512; off<<=1){
    int a = (t>=off) ? sm[t-off] : 0;
    __syncthreads();
    sm[t] += a;
    __syncthreads();
  }
  int excl = beg + sm[t] - v;
  cur[t] = excl;
  if(lo + t < n) row_off[lo + t] = excl;
  if(k == nbk-1 && t == 0) row_off[n] = ne;
  __syncthreads();
  for(int e = beg + t; e < end; e += 512){
    int2 sd = ebuf[e];
    int pos = atomicAdd(&cur[sd.y - lo], 1);
    csr[pos] = sd.x;
  }
}

// ---------------- feature prep ----------------
// A0 row layout: [mean(128) | x(128)] bf16, stride 256. Writes x part.
__global__ void k_cast_x(const float* emb, const int* n_id, unsigned short* A0, int n){
  int gid = blockIdx.x*256 + threadIdx.x;      // n*32 threads, 4 cols each
  int row = gid >> 5, c4 = (gid & 31) * 4;
  if(row >= n) return;
  float4 v = *(const float4*)&emb[(long)n_id[row]*128 + c4];
  ushort4 o;
  o.x = f2bf(v.x); o.y = f2bf(v.y); o.z = f2bf(v.z); o.w = f2bf(v.w);
  *(ushort4*)&A0[(long)row*256 + 128 + c4] = o;
}

// wcat[n][k] = bf16( k<128 ? Wl[n][k] : Wr[n][k-128] ), [128][256]
__global__ void k_wcat(const float* Wl, const float* Wr, unsigned short* wc){
  int i = blockIdx.x*256 + threadIdx.x;
  if(i >= 128*256) return;
  int nn = i >> 8, k = i & 255;
  float v = (k<128) ? Wl[nn*128 + k] : Wr[nn*128 + k - 128];
  wc[i] = f2bf(v);
}

// ---------------- mean aggregation: one wave per node, 8-deep gather pipeline ----------------
__global__ void k_agg(const unsigned short* X, unsigned short* Mout,
                      const int* row_off, const int* csr, int n){
  int w = (blockIdx.x*blockDim.x + threadIdx.x) >> 6;
  int lane = threadIdx.x & 63;
  if(w >= n) return;
  int beg = row_off[w], end = row_off[w+1];
  int deg = end - beg;
  float a0 = 0.f, a1 = 0.f;
  const char* Xb = (const char*)X + 256;     // x-half of the 512B row
  for(int base=0; base<deg; base+=64){
    int cnt = deg - base; if(cnt>64) cnt=64;
    int c1 = cnt - 1;
    // one coalesced load stages up to 64 indices into a register
    int idx = csr[beg + base + (lane < cnt ? lane : c1)];
    for(int j=0; j<cnt; j+=8){
      int j1=j+1>c1?c1:j+1, j2=j+2>c1?c1:j+2, j3=j+3>c1?c1:j+3;
      int j4=j+4>c1?c1:j+4, j5=j+5>c1?c1:j+5, j6=j+6>c1?c1:j+6, j7=j+7>c1?c1:j+7;
      int s0 = __builtin_amdgcn_readlane(idx, j);
      int s1 = __builtin_amdgcn_readlane(idx, j1);
      int s2 = __builtin_amdgcn_readlane(idx, j2);
      int s3 = __builtin_amdgcn_readlane(idx, j3);
      int s4 = __builtin_amdgcn_readlane(idx, j4);
      int s5 = __builtin_amdgcn_readlane(idx, j5);
      int s6 = __builtin_amdgcn_readlane(idx, j6);
      int s7 = __builtin_amdgcn_readlane(idx, j7);
      unsigned int v0 = ((const unsigned int*)(Xb + (long)s0*512))[lane];
      unsigned int v1 = ((const unsigned int*)(Xb + (long)s1*512))[lane];
      unsigned int v2 = ((const unsigned int*)(Xb + (long)s2*512))[lane];
      unsigned int v3 = ((const unsigned int*)(Xb + (long)s3*512))[lane];
      unsigned int v4 = ((const unsigned int*)(Xb + (long)s4*512))[lane];
      unsigned int v5 = ((const unsigned int*)(Xb + (long)s5*512))[lane];
      unsigned int v6 = ((const unsigned int*)(Xb + (long)s6*512))[lane];
      unsigned int v7 = ((const unsigned int*)(Xb + (long)s7*512))[lane];
      acc2(v0, a0, a1);
      if(j+1<cnt) acc2(v1, a0, a1);
      if(j+2<cnt) acc2(v2, a0, a1);
      if(j+3<cnt) acc2(v3, a0, a1);
      if(j+4<cnt) acc2(v4, a0, a1);
      if(j+5<cnt) acc2(v5, a0, a1);
      if(j+6<cnt) acc2(v6, a0, a1);
      if(j+7<cnt) acc2(v7, a0, a1);
    }
  }
  float inv = (deg>0) ? 1.0f/(float)deg : 0.f;
  a0 *= inv; a1 *= inv;
  unsigned int o = ((unsigned int)f2bf(a1) << 16) | (unsigned int)f2bf(a0);
  *(unsigned int*)((char*)Mout + (long)w*512 + lane*4) = o;
}

// ---------------- GEMM: C[M,128] = A[M,256] @ Wcat^T + bias ----------------
// block = 256 thr = 4 waves; 256 rows per block (4 row-tiles of 64), W staged once.
template<int RELU, int OUTSTRIDE, int OUTOFF>
__global__ __launch_bounds__(256,2) void k_gemm(const unsigned short* A,
                                                const unsigned short* wc,
                                                const float* bias,
                                                unsigned short* out, int nrows){
  __shared__ unsigned short Wl[32768];   // 128 rows x 256 cols bf16 = 64KB
  int tid = threadIdx.x;
  // stage W into LDS with st-swizzle: byte ^= (row&7)<<4
  for(int it=0; it<16; ++it){
    int idx  = it*256 + tid;       // 16B chunk id, 4096 total
    int byte = idx*16;
    int row  = byte >> 9;
    int swz  = byte ^ ((row & 7) << 4);
    *(uint4*)((char*)Wl + swz) = *(const uint4*)((const char*)wc + byte);
  }
  __syncthreads();

  int lane = tid & 63, wv = tid >> 6;
  // hoist bias (per nf fragment, col = nf*16 + (lane&15))
  float bs[8];
#pragma unroll
  for(int nf=0; nf<8; ++nf) bs[nf] = bias[nf*16 + (lane & 15)];

  for(int t=0; t<4; ++t){
    int rowA = blockIdx.x*256 + t*64 + wv*16 + (lane & 15);
    int rcl  = rowA < nrows ? rowA : nrows-1;
    const char* Ab = (const char*)(A + (long)rcl*256) + ((lane>>4)*16);
    bf16x8 a[8];
#pragma unroll
    for(int k=0;k<8;++k) a[k] = *(const bf16x8*)(Ab + k*64);

    f32x4 acc[8];
#pragma unroll
    for(int i=0;i<8;++i) acc[i] = (f32x4){0.f,0.f,0.f,0.f};

#pragma unroll
    for(int nf=0; nf<8; ++nf){
      int rw = nf*16 + (lane & 15);
#pragma unroll
      for(int k=0;k<8;++k){
        int byte = (rw*512 + k*64 + (lane>>4)*16) ^ ((rw & 7) << 4);
        bf16x8 b = *(const bf16x8*)((const char*)Wl + byte);
        acc[nf] = __builtin_amdgcn_mfma_f32_16x16x32_bf16(a[k], b, acc[nf], 0, 0, 0);
      }
    }

    int rbase = blockIdx.x*256 + t*64 + wv*16 + (lane>>4)*4;
#pragma unroll
    for(int nf=0; nf<8; ++nf){
      int col = nf*16 + (lane & 15);
#pragma unroll
      for(int r=0;r<4;++r){
        int row = rbase + r;
        if(row < nrows){
          float v = acc[nf][r] + bs[nf];
          if(RELU) v = v > 0.f ? v : 0.f;
          out[(long)row*OUTSTRIDE + OUTOFF + col] = f2bf(v);
        }
      }
    }
  }
}

// ---------------- edge-label dot: 4 pairs per wave, 16 lanes x 16B per row ----------------
__global__ void k_dot(const unsigned short* z, const int* s, const int* d,
                      float* out, int nl){
  int wv = (blockIdx.x*256 + threadIdx.x) >> 6;   // wave id
  int lane = threadIdx.x & 63;
  int g = lane >> 4;                               // group 0..3 (one pair each)
  int gl = lane & 15;                              // lane within group
  int pi = wv*4 + g;
  float acc = 0.f;
  if(pi < nl){
    int si = s[pi], di = d[pi];
    bf16x8 va = *(const bf16x8*)&z[(long)si*128 + gl*8];
    bf16x8 vb = *(const bf16x8*)&z[(long)di*128 + gl*8];
#pragma unroll
    for(int i=0;i<8;++i)
      acc += bf2f((unsigned short)va[i]) * bf2f((unsigned short)vb[i]);
#pragma unroll
    for(int off=1; off<16; off<<=1)
      acc += __shfl_xor(acc, off, 16);
    if(gl==0) out[pi] = acc;
  }
}

extern "C" void kernel_launch(void* const* d_in, const int* in_sizes, int n_in,
                              void* d_out, int out_size, void* d_ws, size_t ws_size,
                              hipStream_t stream){
  const int N  = in_sizes[0];
  const int NE = in_sizes[1] / 2;
  const int NL = in_sizes[2] / 2;
  const int*   n_id = (const int*)d_in[0];
  const int*   src  = (const int*)d_in[1];
  const int*   dst  = src + NE;
  const int*   ls   = (const int*)d_in[2];
  const int*   ld   = ls + NL;
  const float* emb  = (const float*)d_in[3];
  const float* Wl0  = (const float*)d_in[4];
  const float* bl0  = (const float*)d_in[5];
  const float* Wr0  = (const float*)d_in[6];
  const float* Wl1  = (const float*)d_in[7];
  const float* bl1  = (const float*)d_in[8];
  const float* Wr1  = (const float*)d_in[9];
  float* out = (float*)d_out;

  char* ws = (char*)d_ws;
  size_t off = 0;
  auto alloc = [&](size_t bytes)->char*{
    char* p = ws + off;
    off = (off + bytes + 255) & ~(size_t)255;
    return p;
  };
  unsigned short* A0   = (unsigned short*)alloc((size_t)N*256*2);   // [mean0|x]
  unsigned short* A1   = (unsigned short*)alloc((size_t)N*256*2);   // [mean1|h]
  int* row_off         = (int*)alloc((size_t)(N+1)*4);
  int* csr             = (int*)alloc((size_t)NE*4);
  int* gcount          = (int*)alloc(MAXBKT*4);
  int* gbase           = (int*)alloc(MAXBKT*4);
  int* gcursor         = (int*)alloc(MAXBKT*4);
  unsigned short* wc0  = (unsigned short*)alloc(128*256*2);
  unsigned short* wc1  = (unsigned short*)alloc(128*256*2);
  int2* ebuf           = (int2*)A1;      // 12.8MB overlay, dead before gemm0
  unsigned short* Z    = A0;             // reuse A0 for z [N][128]

  const int NBK = (N + BKT_RANGE - 1) >> BKT_SHIFT;   // <= 256
  const int NCH = (NE + 4095) / 4096;

  hipLaunchKernelGGL(k_zero,     dim3(1),            dim3(256), 0, stream, gcount, NBK);
  hipLaunchKernelGGL(k_bcount,   dim3(NCH),          dim3(256), 0, stream, dst, gcount, NE, NBK);
  hipLaunchKernelGGL(k_bscan,    dim3(1),            dim3(256), 0, stream, gcount, gbase, gcursor, NBK);
  hipLaunchKernelGGL(k_bscatter, dim3(NCH),          dim3(256), 0, stream, src, dst, gcursor, ebuf, NE, NBK);
  hipLaunchKernelGGL(k_bsort,    dim3(NBK),          dim3(512), 0, stream, ebuf, gbase, gcursor, csr, row_off, N, NE, NBK);
  hipLaunchKernelGGL(k_cast_x,   dim3((N*32+255)/256),dim3(256), 0, stream, emb, n_id, A0, N);
  hipLaunchKernelGGL(k_wcat,     dim3(128),          dim3(256), 0, stream, Wl0, Wr0, wc0);
  hipLaunchKernelGGL(k_wcat,     dim3(128),          dim3(256), 0, stream, Wl1, Wr1, wc1);
  // layer 0
  hipLaunchKernelGGL(k_agg,      dim3((N*64+255)/256),dim3(256), 0, stream, A0, A0, row_off, csr, N);
  hipLaunchKernelGGL((k_gemm<1,256,128>), dim3((N+255)/256), dim3(256), 0, stream, A0, wc0, bl0, A1, N);
  // layer 1
  hipLaunchKernelGGL(k_agg,      dim3((N*64+255)/256),dim3(256), 0, stream, A1, A1, row_off, csr, N);
  hipLaunchKernelGGL((k_gemm<0,128,0>),   dim3((N+255)/256), dim3(256), 0, stream, A1, wc1, bl1, Z, N);
  // edge-label dots
  hipLaunchKernelGGL(k_dot,      dim3((NL+15)/16),   dim3(256), 0, stream, Z, ls, ld, out, NL);
}

// Round 5
// 269.916 us; speedup vs baseline: 2.2723x; 1.0211x over previous
//
#include <hip/hip_runtime.h>
#include <hip/hip_bf16.h>

typedef short bf16x8 __attribute__((ext_vector_type(8)));
typedef float f32x4 __attribute__((ext_vector_type(4)));
typedef float f32x2 __attribute__((ext_vector_type(2)));

#define BKT_SHIFT 9
#define BKT_RANGE 512          // nodes per bucket
#define MAXBKT 256             // N <= 131072

__device__ __forceinline__ float bf2f(unsigned short u){
  union { unsigned int i; float f; } v; v.i = ((unsigned int)u)<<16; return v.f;
}
__device__ __forceinline__ unsigned short f2bf(float f){
  union { float f; unsigned int i; } v; v.f = f;
  unsigned int i = v.i;
  return (unsigned short)((i + 0x7fffu + ((i>>16)&1u)) >> 16);  // RNE
}
// unpack 2 packed bf16 into float2 {lo, hi}: 2 VALU (shl, and)
__device__ __forceinline__ f32x2 up2(unsigned int v){
  union { unsigned int i; float f; } lo, hi;
  lo.i = v << 16; hi.i = v & 0xffff0000u;
  return (f32x2){lo.f, hi.f};
}

// ---------------- bucket-sort CSR build ----------------
__global__ void k_zero(int* p, int n){
  int i = blockIdx.x*256 + threadIdx.x;
  if(i<n) p[i] = 0;
}

// B1: per-block LDS histogram of dst-buckets -> global bucket counts
__global__ void k_bcount(const int* dst, int* gcount, int ne, int nbk){
  __shared__ int cnt[MAXBKT];
  int tid = threadIdx.x;
  if(tid < nbk) cnt[tid] = 0;
  __syncthreads();
  int base = blockIdx.x * 4096;
#pragma unroll
  for(int i=0;i<16;++i){
    int e = base + i*256 + tid;
    if(e < ne) atomicAdd(&cnt[dst[e] >> BKT_SHIFT], 1);
  }
  __syncthreads();
  if(tid < nbk && cnt[tid] > 0) atomicAdd(&gcount[tid], cnt[tid]);
}

// B2: exclusive scan of bucket counts -> base & cursor
__global__ void k_bscan(const int* gcount, int* gbase, int* gcursor, int nbk){
  __shared__ int sm[256];
  int t = threadIdx.x;
  int v = (t<nbk) ? gcount[t] : 0;
  sm[t] = v;
  __syncthreads();
  for(int off=1; off<256; off<<=1){
    int a = (t>=off) ? sm[t-off] : 0;
    __syncthreads();
    sm[t] += a;
    __syncthreads();
  }
  if(t<nbk){
    int excl = sm[t] - v;
    gbase[t] = excl;
    gcursor[t] = excl;
  }
}

// B3: scatter (s,d) into bucket-partitioned ebuf via LDS ranking
__global__ void k_bscatter(const int* src, const int* dst, int* gcursor,
                           int2* ebuf, int ne, int nbk){
  __shared__ int cnt[MAXBKT];
  __shared__ int runbase[MAXBKT];
  int tid = threadIdx.x;
  if(tid < nbk) cnt[tid] = 0;
  __syncthreads();
  int base = blockIdx.x * 4096;
  int se[16], de[16], re[16];
#pragma unroll
  for(int i=0;i<16;++i){
    int e = base + i*256 + tid;
    if(e < ne){
      de[i] = dst[e];
      se[i] = src[e];
      re[i] = atomicAdd(&cnt[de[i] >> BKT_SHIFT], 1);
    } else de[i] = -1;
  }
  __syncthreads();
  if(tid < nbk) runbase[tid] = cnt[tid] ? atomicAdd(&gcursor[tid], cnt[tid]) : 0;
  __syncthreads();
#pragma unroll
  for(int i=0;i<16;++i){
    if(de[i] >= 0){
      int pos = runbase[de[i] >> BKT_SHIFT] + re[i];
      ebuf[pos] = make_int2(se[i], de[i]);
    }
  }
}

// B4: per-bucket counting sort -> csr + row_off. grid = nbk, block = 512.
__global__ void k_bsort(const int2* ebuf, const int* gbase, const int* gcursor,
                        int* csr, int* row_off, int n, int ne, int nbk){
  __shared__ int h[BKT_RANGE];
  __shared__ int cur[BKT_RANGE];
  int t = threadIdx.x;
  int k = blockIdx.x;
  int lo = k << BKT_SHIFT;
  int beg = gbase[k], end = gcursor[k];
  h[t] = 0;
  __syncthreads();
  for(int e = beg + t; e < end; e += 512)
    atomicAdd(&h[ebuf[e].y - lo], 1);
  __syncthreads();
  int v = h[t];
  // inclusive scan over 512
  __shared__ int sm[512];
  sm[t] = v;
  __syncthreads();
  for(int off=1; off<512; off<<=1){
    int a = (t>=off) ? sm[t-off] : 0;
    __syncthreads();
    sm[t] += a;
    __syncthreads();
  }
  int excl = beg + sm[t] - v;
  cur[t] = excl;
  if(lo + t < n) row_off[lo + t] = excl;
  if(k == nbk-1 && t == 0) row_off[n] = ne;
  __syncthreads();
  for(int e = beg + t; e < end; e += 512){
    int2 sd = ebuf[e];
    int pos = atomicAdd(&cur[sd.y - lo], 1);
    csr[pos] = sd.x;
  }
}

// ---------------- fused prep: wc0 | wc1 | cast_x ----------------
// blocks [0,128): wc0, [128,256): wc1, [256,...): cast_x
__global__ void k_prep(const float* emb, const int* n_id, unsigned short* A0,
                       const float* Wl0, const float* Wr0, unsigned short* wc0,
                       const float* Wl1, const float* Wr1, unsigned short* wc1,
                       int n){
  int b = blockIdx.x;
  if(b < 256){
    const float* Wl = (b < 128) ? Wl0 : Wl1;
    const float* Wr = (b < 128) ? Wr0 : Wr1;
    unsigned short* wc = (b < 128) ? wc0 : wc1;
    int i = (b & 127)*256 + threadIdx.x;
    int nn = i >> 8, k = i & 255;
    float v = (k<128) ? Wl[nn*128 + k] : Wr[nn*128 + k - 128];
    wc[i] = f2bf(v);
  } else {
    int gid = (b-256)*256 + threadIdx.x;
    int row = gid >> 5, c4 = (gid & 31) * 4;
    if(row >= n) return;
    float4 v = *(const float4*)&emb[(long)n_id[row]*128 + c4];
    ushort4 o;
    o.x = f2bf(v.x); o.y = f2bf(v.y); o.z = f2bf(v.z); o.w = f2bf(v.w);
    *(ushort4*)&A0[(long)row*256 + 128 + c4] = o;
  }
}

// ---------------- mean aggregation: one wave per node, scalar addressing ----------------
// w forced wave-uniform via readfirstlane -> csr[e] becomes s_load, row base in
// SGPRs, per-lane voffset fixed. Per-edge VALU: shl+and+(pk_)add only.
__global__ void k_agg(const unsigned short* X, unsigned short* Mout,
                      const int* row_off, const int* csr, int n){
  int w = __builtin_amdgcn_readfirstlane((int)((blockIdx.x*blockDim.x + threadIdx.x) >> 6));
  int lane = threadIdx.x & 63;
  if(w >= n) return;
  int beg = row_off[w], end = row_off[w+1];
  int deg = end - beg;
  f32x2 acc = {0.f, 0.f};
  const char* Xb = (const char*)X + 256;     // x-half of the 512B row
  int e = beg;
  for(; e + 8 <= end; e += 8){
    unsigned int v0 = ((const unsigned int*)(Xb + (long)csr[e  ]*512))[lane];
    unsigned int v1 = ((const unsigned int*)(Xb + (long)csr[e+1]*512))[lane];
    unsigned int v2 = ((const unsigned int*)(Xb + (long)csr[e+2]*512))[lane];
    unsigned int v3 = ((const unsigned int*)(Xb + (long)csr[e+3]*512))[lane];
    unsigned int v4 = ((const unsigned int*)(Xb + (long)csr[e+4]*512))[lane];
    unsigned int v5 = ((const unsigned int*)(Xb + (long)csr[e+5]*512))[lane];
    unsigned int v6 = ((const unsigned int*)(Xb + (long)csr[e+6]*512))[lane];
    unsigned int v7 = ((const unsigned int*)(Xb + (long)csr[e+7]*512))[lane];
    acc += up2(v0); acc += up2(v1); acc += up2(v2); acc += up2(v3);
    acc += up2(v4); acc += up2(v5); acc += up2(v6); acc += up2(v7);
  }
  for(; e + 4 <= end; e += 4){
    unsigned int v0 = ((const unsigned int*)(Xb + (long)csr[e  ]*512))[lane];
    unsigned int v1 = ((const unsigned int*)(Xb + (long)csr[e+1]*512))[lane];
    unsigned int v2 = ((const unsigned int*)(Xb + (long)csr[e+2]*512))[lane];
    unsigned int v3 = ((const unsigned int*)(Xb + (long)csr[e+3]*512))[lane];
    acc += up2(v0); acc += up2(v1); acc += up2(v2); acc += up2(v3);
  }
  for(; e < end; ++e){
    unsigned int v = ((const unsigned int*)(Xb + (long)csr[e]*512))[lane];
    acc += up2(v);
  }
  float inv = (deg>0) ? 1.0f/(float)deg : 0.f;
  float a0 = acc[0]*inv, a1 = acc[1]*inv;
  unsigned int o = ((unsigned int)f2bf(a1) << 16) | (unsigned int)f2bf(a0);
  *(unsigned int*)((char*)Mout + (long)w*512 + lane*4) = o;
}

// ---------------- GEMM: C[M,128] = A[M,256] @ Wcat^T + bias ----------------
// block = 256 thr = 4 waves; 256 rows per block (4 row-tiles of 64), W staged once.
template<int RELU, int OUTSTRIDE, int OUTOFF>
__global__ __launch_bounds__(256,2) void k_gemm(const unsigned short* A,
                                                const unsigned short* wc,
                                                const float* bias,
                                                unsigned short* out, int nrows){
  __shared__ unsigned short Wl[32768];   // 128 rows x 256 cols bf16 = 64KB
  int tid = threadIdx.x;
  // stage W into LDS with st-swizzle: byte ^= (row&7)<<4
  for(int it=0; it<16; ++it){
    int idx  = it*256 + tid;       // 16B chunk id, 4096 total
    int byte = idx*16;
    int row  = byte >> 9;
    int swz  = byte ^ ((row & 7) << 4);
    *(uint4*)((char*)Wl + swz) = *(const uint4*)((const char*)wc + byte);
  }
  __syncthreads();

  int lane = tid & 63, wv = tid >> 6;
  // hoist bias (per nf fragment, col = nf*16 + (lane&15))
  float bs[8];
#pragma unroll
  for(int nf=0; nf<8; ++nf) bs[nf] = bias[nf*16 + (lane & 15)];

  for(int t=0; t<4; ++t){
    int rowA = blockIdx.x*256 + t*64 + wv*16 + (lane & 15);
    int rcl  = rowA < nrows ? rowA : nrows-1;
    const char* Ab = (const char*)(A + (long)rcl*256) + ((lane>>4)*16);
    bf16x8 a[8];
#pragma unroll
    for(int k=0;k<8;++k) a[k] = *(const bf16x8*)(Ab + k*64);

    f32x4 acc[8];
#pragma unroll
    for(int i=0;i<8;++i) acc[i] = (f32x4){0.f,0.f,0.f,0.f};

#pragma unroll
    for(int nf=0; nf<8; ++nf){
      int rw = nf*16 + (lane & 15);
#pragma unroll
      for(int k=0;k<8;++k){
        int byte = (rw*512 + k*64 + (lane>>4)*16) ^ ((rw & 7) << 4);
        bf16x8 b = *(const bf16x8*)((const char*)Wl + byte);
        acc[nf] = __builtin_amdgcn_mfma_f32_16x16x32_bf16(a[k], b, acc[nf], 0, 0, 0);
      }
    }

    int rbase = blockIdx.x*256 + t*64 + wv*16 + (lane>>4)*4;
#pragma unroll
    for(int nf=0; nf<8; ++nf){
      int col = nf*16 + (lane & 15);
#pragma unroll
      for(int r=0;r<4;++r){
        int row = rbase + r;
        if(row < nrows){
          float v = acc[nf][r] + bs[nf];
          if(RELU) v = v > 0.f ? v : 0.f;
          out[(long)row*OUTSTRIDE + OUTOFF + col] = f2bf(v);
        }
      }
    }
  }
}

// ---------------- edge-label dot: 4 pairs per wave, 16 lanes x 16B per row ----------------
__global__ void k_dot(const unsigned short* z, const int* s, const int* d,
                      float* out, int nl){
  int wv = (blockIdx.x*256 + threadIdx.x) >> 6;   // wave id
  int lane = threadIdx.x & 63;
  int g = lane >> 4;                               // group 0..3 (one pair each)
  int gl = lane & 15;                              // lane within group
  int pi = wv*4 + g;
  float acc = 0.f;
  if(pi < nl){
    int si = s[pi], di = d[pi];
    bf16x8 va = *(const bf16x8*)&z[(long)si*128 + gl*8];
    bf16x8 vb = *(const bf16x8*)&z[(long)di*128 + gl*8];
#pragma unroll
    for(int i=0;i<8;++i)
      acc += bf2f((unsigned short)va[i]) * bf2f((unsigned short)vb[i]);
#pragma unroll
    for(int off=1; off<16; off<<=1)
      acc += __shfl_xor(acc, off, 16);
    if(gl==0) out[pi] = acc;
  }
}

extern "C" void kernel_launch(void* const* d_in, const int* in_sizes, int n_in,
                              void* d_out, int out_size, void* d_ws, size_t ws_size,
                              hipStream_t stream){
  const int N  = in_sizes[0];
  const int NE = in_sizes[1] / 2;
  const int NL = in_sizes[2] / 2;
  const int*   n_id = (const int*)d_in[0];
  const int*   src  = (const int*)d_in[1];
  const int*   dst  = src + NE;
  const int*   ls   = (const int*)d_in[2];
  const int*   ld   = ls + NL;
  const float* emb  = (const float*)d_in[3];
  const float* Wl0  = (const float*)d_in[4];
  const float* bl0  = (const float*)d_in[5];
  const float* Wr0  = (const float*)d_in[6];
  const float* Wl1  = (const float*)d_in[7];
  const float* bl1  = (const float*)d_in[8];
  const float* Wr1  = (const float*)d_in[9];
  float* out = (float*)d_out;

  char* ws = (char*)d_ws;
  size_t off = 0;
  auto alloc = [&](size_t bytes)->char*{
    char* p = ws + off;
    off = (off + bytes + 255) & ~(size_t)255;
    return p;
  };
  unsigned short* A0   = (unsigned short*)alloc((size_t)N*256*2);   // [mean0|x]
  unsigned short* A1   = (unsigned short*)alloc((size_t)N*256*2);   // [mean1|h]
  int* row_off         = (int*)alloc((size_t)(N+1)*4);
  int* csr             = (int*)alloc((size_t)NE*4);
  int* gcount          = (int*)alloc(MAXBKT*4);
  int* gbase           = (int*)alloc(MAXBKT*4);
  int* gcursor         = (int*)alloc(MAXBKT*4);
  unsigned short* wc0  = (unsigned short*)alloc(128*256*2);
  unsigned short* wc1  = (unsigned short*)alloc(128*256*2);
  int2* ebuf           = (int2*)A1;      // 12.8MB overlay, dead before gemm0
  unsigned short* Z    = A0;             // reuse A0 for z [N][128]

  const int NBK = (N + BKT_RANGE - 1) >> BKT_SHIFT;   // <= 256
  const int NCH = (NE + 4095) / 4096;

  hipLaunchKernelGGL(k_zero,     dim3(1),            dim3(256), 0, stream, gcount, NBK);
  hipLaunchKernelGGL(k_bcount,   dim3(NCH),          dim3(256), 0, stream, dst, gcount, NE, NBK);
  hipLaunchKernelGGL(k_bscan,    dim3(1),            dim3(256), 0, stream, gcount, gbase, gcursor, NBK);
  hipLaunchKernelGGL(k_bscatter, dim3(NCH),          dim3(256), 0, stream, src, dst, gcursor, ebuf, NE, NBK);
  hipLaunchKernelGGL(k_bsort,    dim3(NBK),          dim3(512), 0, stream, ebuf, gbase, gcursor, csr, row_off, N, NE, NBK);
  hipLaunchKernelGGL(k_prep,     dim3(256 + (N*32+255)/256), dim3(256), 0, stream,
                     emb, n_id, A0, Wl0, Wr0, wc0, Wl1, Wr1, wc1, N);
  // layer 0
  hipLaunchKernelGGL(k_agg,      dim3((N*64+255)/256),dim3(256), 0, stream, A0, A0, row_off, csr, N);
  hipLaunchKernelGGL((k_gemm<1,256,128>), dim3((N+255)/256), dim3(256), 0, stream, A0, wc0, bl0, A1, N);
  // layer 1
  hipLaunchKernelGGL(k_agg,      dim3((N*64+255)/256),dim3(256), 0, stream, A1, A1, row_off, csr, N);
  hipLaunchKernelGGL((k_gemm<0,128,0>),   dim3((N+255)/256), dim3(256), 0, stream, A1, wc1, bl1, Z, N);
  // edge-label dots
  hipLaunchKernelGGL(k_dot,      dim3((NL+15)/16),   dim3(256), 0, stream, Z, ls, ld, out, NL);
}